// Round 3
// baseline (48.010 us; speedup 1.0000x reference)
//
#include <hip/hip_runtime.h>

// out[j] = input_offset[permute[t]] + (j - output_offset[t]) for table t's
// output segment. Pure streaming int32 write (~268 MB); offsets tiny (cached).
//
// Persistent-grid strategy (fillBuffer-style): 2048 blocks (8/CU, single
// residency wave, no block churn). Each block owns a CONTIGUOUS run of
// 4096-element tiles: one binary search for the first tile, then incremental
// table advance per tile (table len >= 16384 = 4 tiles => at most one advance
// per tile). Min table len > TILE => at most one boundary inside any tile =>
// per-element base is a 2-way select. All main-loop stores aligned dwordx4.

constexpr int BLOCK = 256;            // 4 waves
constexpr int TILE  = 4096;           // elements per tile (16 KB)
constexpr int MAX_BLOCKS = 2048;      // 8 blocks/CU on 256 CUs

__global__ __launch_bounds__(BLOCK) void ramp_persist(
    const int* __restrict__ permute,
    const int* __restrict__ input_offset,
    const int* __restrict__ output_offset,
    int* __restrict__ out,
    int tables, int out_size)
{
    const int ntiles = (out_size + TILE - 1) / TILE;
    const int nb     = gridDim.x;
    const int per    = (ntiles + nb - 1) / nb;
    const int tile0  = blockIdx.x * per;
    const int tile1  = min(tile0 + per, ntiles);
    if (tile0 >= tile1) return;

    // Binary search for the first tile's table: largest t with
    // output_offset[t] <= s. Uniform address -> scalar loads.
    int s = tile0 * TILE;
    int lo = 0, hi = tables;
    while (hi - lo > 1) {
        const int mid = (lo + hi) >> 1;
        if (output_offset[mid] <= s) lo = mid; else hi = mid;
    }
    int t        = lo;
    int boundary = output_offset[t + 1];
    int base0    = input_offset[permute[t]] - output_offset[t];

    const int tid = threadIdx.x;
    int4* __restrict__ out4 = reinterpret_cast<int4*>(out);

    for (int tl = tile0; tl < tile1; ++tl) {
        s = tl * TILE;
        const int e = min(s + TILE, out_size);

        // Incremental advance (at most one step per tile; while for safety).
        while (boundary <= s) {
            ++t;
            base0    = input_offset[permute[t]] - boundary;
            boundary = output_offset[t + 1];
        }
        int base1 = base0;
        if (boundary < e) base1 = input_offset[permute[t + 1]] - boundary;

        const int e4 = e & ~3;
        #pragma unroll
        for (int k = 0; k < TILE / (BLOCK * 4); ++k) {
            const int j = s + (k * BLOCK + tid) * 4;
            if (j < e4) {
                int4 v;
                v.x = ((j    ) < boundary ? base0 : base1) + j;
                v.y = ((j + 1) < boundary ? base0 : base1) + j + 1;
                v.z = ((j + 2) < boundary ? base0 : base1) + j + 2;
                v.w = ((j + 3) < boundary ? base0 : base1) + j + 3;
                out4[j >> 2] = v;
            }
        }
        // Scalar tail (only the global last tile when out_size % 4 != 0).
        const int jt = e4 + tid;
        if (jt < e) out[jt] = ((jt < boundary) ? base0 : base1) + jt;
    }
}

extern "C" void kernel_launch(void* const* d_in, const int* in_sizes, int n_in,
                              void* d_out, int out_size, void* d_ws, size_t ws_size,
                              hipStream_t stream) {
    const int* permute       = (const int*)d_in[0];
    const int* input_offset  = (const int*)d_in[1];
    const int* output_offset = (const int*)d_in[2];
    int* out = (int*)d_out;
    const int tables = in_sizes[0];

    const int ntiles = (out_size + TILE - 1) / TILE;
    const int grid   = ntiles < MAX_BLOCKS ? ntiles : MAX_BLOCKS;
    hipLaunchKernelGGL(ramp_persist, dim3(grid), dim3(BLOCK), 0, stream,
                       permute, input_offset, output_offset, out, tables, out_size);
}